// Round 3
// baseline (23036.151 us; speedup 1.0000x reference)
//
#include <hip/hip_runtime.h>
#include <math.h>

#define DD 512
#define HEADS 8
#define DHD 64
#define MM 256
#define BB 8
#define CH 4
#define NCHUNK 2
#define NINST 6000
#define SIDE 78
#define NSQ 6084
#define NTOK 6085
#define PADF 59
#define NPAD 6144
#define LMM 24
#define RESK 33
#define MAXNN 520
#define KNN 12
#define SLOT 2097152   // 32*256*256 floats: pinv arena slot (per-chunk)

// ---------------- reduction helpers (blockDim == 256 only) ----------------
__device__ __forceinline__ float blockReduceSum(float v, float* red) {
    int t = threadIdx.x;
    red[t] = v; __syncthreads();
    #pragma unroll
    for (int s = 128; s > 0; s >>= 1) { if (t < s) red[t] += red[t + s]; __syncthreads(); }
    float r = red[0]; __syncthreads();
    return r;
}
__device__ __forceinline__ float blockReduceMax(float v, float* red) {
    int t = threadIdx.x;
    red[t] = v; __syncthreads();
    #pragma unroll
    for (int s = 128; s > 0; s >>= 1) { if (t < s) red[t] = fmaxf(red[t], red[t + s]); __syncthreads(); }
    float r = red[0]; __syncthreads();
    return r;
}

// ---------------- diagnostic: ws too small -> report ws_size via out ----------------
__global__ void k_diag(float* __restrict__ out, float v) {
    int t = threadIdx.x;
    if (t < 32) out[t] = v;
}

// ---------------- per-row LN stats (mean, rstd) over h rows ----------------
__global__ __launch_bounds__(256) void k_lnstat(const float* __restrict__ h, float* __restrict__ st) {
    __shared__ float red[256];
    int row = blockIdx.x;                   // b*NTOK + token
    int t = threadIdx.x;
    const float* src = h + (size_t)row * 512;
    float x0 = src[t], x1 = src[t + 256];
    float mean = blockReduceSum(x0 + x1, red) * (1.f / 512.f);
    float d0 = x0 - mean, d1 = x1 - mean;
    float var = blockReduceSum(d0 * d0 + d1 * d1, red) * (1.f / 512.f);
    if (t == 0) { st[(size_t)row * 2] = mean; st[(size_t)row * 2 + 1] = 1.f / sqrtf(var + 1e-5f); }
}

// ---------------- general 64x64-tile f32 GEMM, K=512 ----------------
// mode 1: fc1   : C=relu(A@W+bias) -> h[b, 1+i, :]   (full batch, b0=0)
// mode 2: qkv   : A = LN(h[b0+...]) with front-pad zeros (fused lnstat/lng/lnb);
//                 C=A@W scatter to chunk-local q/k/v (CH,H,NPAD,64); q scaled 0.125
// mode 3: proj  : A gathered from chunk-local gsrc, h[b0+...] += C + bias
__global__ __launch_bounds__(256) void k_gemm(
    const float* __restrict__ A, const float* __restrict__ W,
    const float* __restrict__ bias, int rows, int ldw, int mode, int b0,
    float* __restrict__ hbuf, float* __restrict__ qb, float* __restrict__ kb,
    float* __restrict__ vb, const float* __restrict__ gsrc,
    const float* __restrict__ lng, const float* __restrict__ lnb,
    const float* __restrict__ lnstat)
{
    __shared__ float As[16][64];
    __shared__ float Ws[16][64];
    int t = threadIdx.x;
    int rt = blockIdx.x, ct = blockIdx.y;
    int r0 = rt * 64, c0 = ct * 64;
    int tr = t >> 4, tc = t & 15;
    int lr = t >> 2, lk4 = (t & 3) << 2;
    int grow = r0 + lr;
    bool rowok = grow < rows;
    int gb = 0, gr = 0;
    if (mode == 3 && rowok) { gb = grow / NTOK; gr = grow - gb * NTOK; }
    // mode 2: fused-LN row setup
    const float* hrow = nullptr;
    float mu = 0.f, rsn = 0.f;
    if (mode == 2 && rowok) {
        int b2 = grow / NPAD, n2 = grow - b2 * NPAD;
        if (n2 >= PADF) {
            size_t ridx = (size_t)(b0 + b2) * NTOK + (n2 - PADF);
            hrow = A + ridx * 512;
            mu  = lnstat[ridx * 2];
            rsn = lnstat[ridx * 2 + 1];
        }
    }
    int wkk = t >> 4, wcc = (t & 15) << 2;
    float acc[4][4] = {{0.f}};
    for (int k0 = 0; k0 < 512; k0 += 16) {
        float4 av = make_float4(0.f, 0.f, 0.f, 0.f);
        if (mode == 2) {
            if (hrow) {
                float4 hv = *(const float4*)(hrow + k0 + lk4);
                float4 g4 = *(const float4*)(lng + k0 + lk4);
                float4 b4 = *(const float4*)(lnb + k0 + lk4);
                av.x = (hv.x - mu) * rsn * g4.x + b4.x;
                av.y = (hv.y - mu) * rsn * g4.y + b4.y;
                av.z = (hv.z - mu) * rsn * g4.z + b4.z;
                av.w = (hv.w - mu) * rsn * g4.w + b4.w;
            }
        } else if (rowok) {
            if (mode == 3) {
                int c = k0 + lk4;
                const float* src = gsrc + (((size_t)gb * HEADS + (c >> 6)) * NPAD + (gr + PADF)) * 64 + (c & 63);
                av = *(const float4*)src;
            } else {
                av = *(const float4*)(A + (size_t)grow * 512 + k0 + lk4);
            }
        }
        As[lk4 + 0][lr] = av.x;
        As[lk4 + 1][lr] = av.y;
        As[lk4 + 2][lr] = av.z;
        As[lk4 + 3][lr] = av.w;
        *(float4*)&Ws[wkk][wcc] = *(const float4*)(W + (size_t)(k0 + wkk) * ldw + c0 + wcc);
        __syncthreads();
        #pragma unroll
        for (int kk = 0; kk < 16; ++kk) {
            float a[4], b4[4];
            *(float4*)a  = *(float4*)&As[kk][tr << 2];
            *(float4*)b4 = *(float4*)&Ws[kk][tc << 2];
            #pragma unroll
            for (int i2 = 0; i2 < 4; ++i2)
                #pragma unroll
                for (int j2 = 0; j2 < 4; ++j2)
                    acc[i2][j2] += a[i2] * b4[j2];
        }
        __syncthreads();
    }
    #pragma unroll
    for (int i2 = 0; i2 < 4; ++i2) {
        int row = r0 + (tr << 2) + i2;
        if (row >= rows) continue;
        int b2, r2;
        if (mode == 1)      { b2 = row / NINST; r2 = row - b2 * NINST; }
        else if (mode == 2) { b2 = row / NPAD;  r2 = row - b2 * NPAD; }
        else                { b2 = row / NTOK;  r2 = row - b2 * NTOK; }
        #pragma unroll
        for (int j2 = 0; j2 < 4; ++j2) {
            int col = c0 + (tc << 2) + j2;
            float val = acc[i2][j2];
            if (mode == 1) {
                val += bias[col];
                val = fmaxf(val, 0.f);
                hbuf[((size_t)b2 * NTOK + 1 + r2) * 512 + col] = val;
            } else if (mode == 2) {
                int which = col >> 9, head = (col >> 6) & 7, dh = col & 63;
                float* dst = which == 0 ? qb : (which == 1 ? kb : vb);
                if (which == 0) val *= 0.125f;
                dst[(((size_t)b2 * HEADS + head) * NPAD + r2) * 64 + dh] = val;
            } else {
                size_t o = ((size_t)(b0 + b2) * NTOK + r2) * 512 + col;
                hbuf[o] += val + bias[col];
            }
        }
    }
}

// ---------------- batched 256xNcols GEMM (K=256): C = coefA*A + coefAB*(A@B) ----------------
__global__ __launch_bounds__(256) void k_bgemm(
    const float* __restrict__ A, const float* __restrict__ B,
    float* __restrict__ C, int ncols, float coefA, float coefAB)
{
    __shared__ float As[16][64];
    __shared__ float Bs[16][64];
    int t = threadIdx.x;
    int bat = blockIdx.x, rt = blockIdx.y, ct = blockIdx.z;
    const float* Ab = A + (size_t)bat * 65536;
    const float* Bb = B + (size_t)bat * 256 * ncols;
    float* Cb = C + (size_t)bat * 256 * ncols;
    int r0 = rt * 64, c0 = ct * 64;
    int tr = t >> 4, tc = t & 15, lr = t >> 2, lk4 = (t & 3) << 2;
    int wkk = t >> 4, wcc = (t & 15) << 2;
    float acc[4][4] = {{0.f}};
    for (int k0 = 0; k0 < 256; k0 += 16) {
        float4 av = *(const float4*)(Ab + (size_t)(r0 + lr) * 256 + k0 + lk4);
        As[lk4 + 0][lr] = av.x;
        As[lk4 + 1][lr] = av.y;
        As[lk4 + 2][lr] = av.z;
        As[lk4 + 3][lr] = av.w;
        *(float4*)&Bs[wkk][wcc] = *(const float4*)(Bb + (size_t)(k0 + wkk) * ncols + c0 + wcc);
        __syncthreads();
        #pragma unroll
        for (int kk = 0; kk < 16; ++kk) {
            float a[4], b4[4];
            *(float4*)a  = *(float4*)&As[kk][tr << 2];
            *(float4*)b4 = *(float4*)&Bs[kk][tc << 2];
            #pragma unroll
            for (int i2 = 0; i2 < 4; ++i2)
                #pragma unroll
                for (int j2 = 0; j2 < 4; ++j2)
                    acc[i2][j2] += a[i2] * b4[j2];
        }
        __syncthreads();
    }
    #pragma unroll
    for (int i2 = 0; i2 < 4; ++i2) {
        int row = r0 + (tr << 2) + i2;
        #pragma unroll
        for (int j2 = 0; j2 < 4; ++j2) {
            int col = c0 + (tc << 2) + j2;
            float val = coefAB * acc[i2][j2];
            if (coefA != 0.f) val += coefA * Ab[(size_t)row * 256 + col];
            Cb[(size_t)row * ncols + col] = val;
        }
    }
}

// ---------------- wrap rows + cls token ----------------
__global__ void k_fixup(float* __restrict__ h, const float* __restrict__ cls)
{
    int b = blockIdx.x, r = blockIdx.y, t = threadIdx.x;
    float* dst; const float* src;
    if (r < 84) {
        dst = h + ((size_t)b * NTOK + 6001 + r) * 512;
        src = h + ((size_t)b * NTOK + 1 + r) * 512;
    } else {
        dst = h + (size_t)b * NTOK * 512;
        src = cls;
    }
    dst[t] = src[t]; dst[t + 256] = src[t + 256];
}

// ---------------- landmarks (mean over 24 consecutive rows) ----------------
__global__ void k_landmark(const float* __restrict__ q, const float* __restrict__ k,
                           float* __restrict__ q_l, float* __restrict__ k_l)
{
    int bhm = blockIdx.x;           // bh*256 + m, bh chunk-local (0..31)
    int d = threadIdx.x;            // 64
    int bh = bhm >> 8, m = bhm & 255;
    const float* qs = q + ((size_t)bh * NPAD + m * LMM) * 64 + d;
    const float* ks = k + ((size_t)bh * NPAD + m * LMM) * 64 + d;
    float sq = 0.f, sk = 0.f;
    #pragma unroll
    for (int j = 0; j < LMM; ++j) { sq += qs[(size_t)j * 64]; sk += ks[(size_t)j * 64]; }
    q_l[(size_t)bhm * 64 + d] = sq * (1.f / 24.f);
    k_l[(size_t)bhm * 64 + d] = sk * (1.f / 24.f);
}

// ---------------- attn2 = softmax(q_l @ k_l^T) ----------------
__global__ __launch_bounds__(256) void k_attn2(const float* __restrict__ q_l,
    const float* __restrict__ k_l, float* __restrict__ attn2)
{
    __shared__ float ql[64];
    __shared__ float red[256];
    int bh = blockIdx.x >> 8, i = blockIdx.x & 255;
    int t = threadIdx.x;
    if (t < 64) ql[t] = q_l[((size_t)(bh * 256 + i)) * 64 + t];
    __syncthreads();
    const float4* kr = (const float4*)(k_l + ((size_t)bh * 256 + t) * 64);
    float s = 0.f;
    #pragma unroll
    for (int d4 = 0; d4 < 16; ++d4) {
        float4 kv = kr[d4];
        s += ql[d4 * 4] * kv.x + ql[d4 * 4 + 1] * kv.y + ql[d4 * 4 + 2] * kv.z + ql[d4 * 4 + 3] * kv.w;
    }
    float mx = blockReduceMax(s, red);
    float e = expf(s - mx);
    float S = blockReduceSum(e, red);
    attn2[((size_t)(bh * 256 + i)) * 256 + t] = e / S;
}

// ---------------- pinv init: z0 = x^T / (maxrowsum*maxcolsum) ----------------
__global__ __launch_bounds__(256) void k_pinv_init(const float* __restrict__ x, float* __restrict__ z)
{
    __shared__ float red[256];
    int bh = blockIdx.x, t = threadIdx.x;
    const float* xb = x + (size_t)bh * 65536;
    float rs = 0.f;
    for (int j = 0; j < 256; ++j) rs += xb[t * 256 + j];
    float colv = blockReduceMax(rs, red);
    float cs = 0.f;
    for (int i2 = 0; i2 < 256; ++i2) cs += xb[i2 * 256 + t];
    float rowv = blockReduceMax(cs, red);
    float scale = 1.f / (colv * rowv);
    float* zb = z + (size_t)bh * 65536;
    for (int i2 = 0; i2 < 256; ++i2)
        zb[(size_t)i2 * 256 + t] = xb[(size_t)t * 256 + i2] * scale;
}

// ---------------- fused attn3 softmax @ v ----------------
__global__ __launch_bounds__(256) void k_attn3v(
    const float* __restrict__ q_l, const float* __restrict__ kbuf,
    const float* __restrict__ vbuf, float* __restrict__ out3)
{
    __shared__ float sc[NPAD];
    __shared__ float ql[64];
    __shared__ float red[256];
    int bh = blockIdx.x >> 8, m = blockIdx.x & 255;
    int t = threadIdx.x;
    if (t < 64) ql[t] = q_l[((size_t)(bh * 256 + m)) * 64 + t];
    __syncthreads();
    float lmax = -INFINITY;
    for (int n = t; n < NPAD; n += 256) {
        const float4* kr = (const float4*)(kbuf + ((size_t)bh * NPAD + n) * 64);
        float s = 0.f;
        #pragma unroll
        for (int d4 = 0; d4 < 16; ++d4) {
            float4 kv = kr[d4];
            s += ql[d4 * 4] * kv.x + ql[d4 * 4 + 1] * kv.y + ql[d4 * 4 + 2] * kv.z + ql[d4 * 4 + 3] * kv.w;
        }
        sc[n] = s;
        lmax = fmaxf(lmax, s);
    }
    float mx = blockReduceMax(lmax, red);
    float lsum = 0.f;
    for (int n = t; n < NPAD; n += 256) {
        float e = expf(sc[n] - mx);
        sc[n] = e;
        lsum += e;
    }
    float S = blockReduceSum(lsum, red);
    int d = t & 63, part = t >> 6;
    float acc = 0.f;
    for (int n = part * 1536; n < (part + 1) * 1536; ++n)
        acc += sc[n] * vbuf[((size_t)bh * NPAD + n) * 64 + d];
    red[t] = acc; __syncthreads();
    if (t < 64) {
        float r = red[t] + red[t + 64] + red[t + 128] + red[t + 192];
        out3[((size_t)(bh * 256 + m)) * 64 + d] = r / S;
    }
}

// ---------------- fused attn1 softmax @ w2 + res conv + res_b (in-place over q) ----------------
__global__ __launch_bounds__(256) void k_attn1res(
    const float* __restrict__ qbuf, const float* __restrict__ k_l,
    const float* __restrict__ w2, const float* __restrict__ vbuf,
    const float* __restrict__ res_w, const float* __restrict__ res_b,
    float* __restrict__ outb)
{
    __shared__ float qr[64];
    __shared__ float p[256];
    __shared__ float red[256];
    int idx = blockIdx.x;
    int n = idx % NPAD, bh = idx / NPAD, hh = bh & 7;
    if (n < PADF) return;
    int t = threadIdx.x;
    if (t < 64) qr[t] = qbuf[((size_t)bh * NPAD + n) * 64 + t];
    __syncthreads();
    const float4* kr = (const float4*)(k_l + ((size_t)bh * 256 + t) * 64);
    float s = 0.f;
    #pragma unroll
    for (int d4 = 0; d4 < 16; ++d4) {
        float4 kv = kr[d4];
        s += qr[d4 * 4] * kv.x + qr[d4 * 4 + 1] * kv.y + qr[d4 * 4 + 2] * kv.z + qr[d4 * 4 + 3] * kv.w;
    }
    float mx = blockReduceMax(s, red);
    float e = expf(s - mx);
    float S = blockReduceSum(e, red);
    p[t] = e / S;
    __syncthreads();
    int d = t & 63, part = t >> 6;
    float acc = 0.f;
    for (int m2 = part * 64; m2 < part * 64 + 64; ++m2)
        acc += p[m2] * w2[((size_t)bh * 256 + m2) * 64 + d];
    red[t] = acc; __syncthreads();
    if (t < 64) {
        float r = red[t] + red[t + 64] + red[t + 128] + red[t + 192];
        float rc = 0.f;
        #pragma unroll
        for (int j = 0; j < RESK; ++j) {
            int nn = n - 16 + j;
            if (nn >= 0 && nn < NPAD)
                rc += vbuf[((size_t)bh * NPAD + nn) * 64 + d] * res_w[hh * RESK + j];
        }
        r += rc + res_b[hh];
        outb[((size_t)bh * NPAD + n) * 64 + d] = r;
    }
}

// ---------------- PPEG: per (b, channel), 78x78 depthwise 7/5/3 ----------------
__global__ __launch_bounds__(256) void k_ppeg(float* __restrict__ h,
    const float* __restrict__ w7, const float* __restrict__ b7,
    const float* __restrict__ w5, const float* __restrict__ b5,
    const float* __restrict__ w3, const float* __restrict__ b3)
{
    __shared__ float f[NSQ];
    __shared__ float wt[83];
    int bc = blockIdx.x;
    int b = bc >> 9, c = bc & 511;
    int t = threadIdx.x;
    float* base = h + ((size_t)b * NTOK + 1) * 512 + c;
    for (int p2 = t; p2 < NSQ; p2 += 256) f[p2] = base[(size_t)p2 * 512];
    if (t < 49) wt[t] = w7[c * 49 + t];
    else if (t >= 64 && t < 89) wt[49 + (t - 64)] = w5[c * 25 + (t - 64)];
    else if (t >= 128 && t < 137) wt[74 + (t - 128)] = w3[c * 9 + (t - 128)];
    __syncthreads();
    float bsum = b7[c] + b5[c] + b3[c];
    for (int p2 = t; p2 < NSQ; p2 += 256) {
        int r = p2 / SIDE, s = p2 - r * SIDE;
        float acc = f[p2] + bsum;
        for (int dy = -3; dy <= 3; ++dy) {
            int rr = r + dy; if (rr < 0 || rr >= SIDE) continue;
            for (int dx = -3; dx <= 3; ++dx) {
                int ss = s + dx; if (ss < 0 || ss >= SIDE) continue;
                acc += f[rr * SIDE + ss] * wt[(dy + 3) * 7 + (dx + 3)];
            }
        }
        for (int dy = -2; dy <= 2; ++dy) {
            int rr = r + dy; if (rr < 0 || rr >= SIDE) continue;
            for (int dx = -2; dx <= 2; ++dx) {
                int ss = s + dx; if (ss < 0 || ss >= SIDE) continue;
                acc += f[rr * SIDE + ss] * wt[49 + (dy + 2) * 5 + (dx + 2)];
            }
        }
        for (int dy = -1; dy <= 1; ++dy) {
            int rr = r + dy; if (rr < 0 || rr >= SIDE) continue;
            for (int dx = -1; dx <= 1; ++dx) {
                int ss = s + dx; if (ss < 0 || ss >= SIDE) continue;
                acc += f[rr * SIDE + ss] * wt[74 + (dy + 1) * 3 + (dx + 1)];
            }
        }
        base[(size_t)p2 * 512] = acc;
    }
}

// ---------------- final LN of cls token ----------------
__global__ __launch_bounds__(256) void k_bag(const float* __restrict__ h,
    const float* __restrict__ g, const float* __restrict__ be, float* __restrict__ bag)
{
    __shared__ float red[256];
    int b = blockIdx.x, t = threadIdx.x;
    const float* src = h + (size_t)b * NTOK * 512;
    float x0 = src[t], x1 = src[t + 256];
    float mean = blockReduceSum(x0 + x1, red) * (1.f / 512.f);
    float d0 = x0 - mean, d1 = x1 - mean;
    float var = blockReduceSum(d0 * d0 + d1 * d1, red) * (1.f / 512.f);
    float rs = 1.f / sqrtf(var + 1e-5f);
    bag[b * 512 + t]       = d0 * rs * g[t] + be[t];
    bag[b * 512 + t + 256] = d1 * rs * g[t + 256] + be[t + 256];
}

__global__ void k_mlp(const float* __restrict__ bag, const float* __restrict__ fc2w,
                      const float* __restrict__ fc2b, float* __restrict__ out)
{
    int t = threadIdx.x;
    if (t < 16) {
        int b = t >> 1, c = t & 1;
        float val = fc2b[c];
        for (int k2 = 0; k2 < 512; ++k2) val += bag[b * 512 + k2] * fc2w[k2 * 2 + c];
        out[b * 2 + c] = val;
    }
}

__global__ __launch_bounds__(256) void k_xcat(const float* __restrict__ bag,
    const float* __restrict__ reh, float* __restrict__ xn)
{
    __shared__ float red[256];
    int i = blockIdx.x, t = threadIdx.x;
    const float* src = (i < BB) ? (bag + (size_t)i * 512) : (reh + (size_t)(i - BB) * 512);
    float x0 = src[t], x1 = src[t + 256];
    float nrm = sqrtf(blockReduceSum(x0 * x0 + x1 * x1, red));
    float inv = 1.f / (nrm + 1e-8f);
    xn[(size_t)i * 512 + t]       = x0 * inv;
    xn[(size_t)i * 512 + t + 256] = x1 * inv;
}

// ---------------- sim row + top-12 (ties -> lowest index) ----------------
__global__ __launch_bounds__(256) void k_sim_topk(const float* __restrict__ xn,
    int* __restrict__ idxb, float* __restrict__ wgt, float* __restrict__ dinvb)
{
    __shared__ float xi[512];
    __shared__ float s[MAXNN];
    __shared__ float redv[256];
    __shared__ int redi[256];
    int i = blockIdx.x, t = threadIdx.x;
    xi[t] = xn[(size_t)i * 512 + t];
    xi[t + 256] = xn[(size_t)i * 512 + t + 256];
    __syncthreads();
    for (int j = t; j < MAXNN; j += 256) {
        const float4* xj = (const float4*)(xn + (size_t)j * 512);
        float dot = 0.f;
        for (int d4 = 0; d4 < 128; ++d4) {
            float4 a4 = xj[d4];
            dot += xi[d4 * 4] * a4.x + xi[d4 * 4 + 1] * a4.y + xi[d4 * 4 + 2] * a4.z + xi[d4 * 4 + 3] * a4.w;
        }
        s[j] = dot - (j == i ? 1e9f : 0.f);
    }
    __syncthreads();
    float degsum = 0.f;
    for (int kk = 0; kk < KNN; ++kk) {
        float bv = -INFINITY; int bi = MAXNN;
        for (int j = t; j < MAXNN; j += 256) {
            float vv = s[j];
            if (vv > bv) { bv = vv; bi = j; }
        }
        redv[t] = bv; redi[t] = bi; __syncthreads();
        for (int st = 128; st > 0; st >>= 1) {
            if (t < st) {
                float v2 = redv[t + st]; int j2 = redi[t + st];
                if (v2 > redv[t] || (v2 == redv[t] && j2 < redi[t])) { redv[t] = v2; redi[t] = j2; }
            }
            __syncthreads();
        }
        int sel = redi[0]; float val = redv[0];
        if (t == 0) {
            idxb[i * KNN + kk] = sel;
            float w = fmaxf(val, 0.f);
            wgt[i * KNN + kk] = w;
            degsum += w;
            s[sel] = -INFINITY;
            if (kk == KNN - 1) dinvb[i] = 1.f / sqrtf(1.f + degsum);
        }
        __syncthreads();
    }
}

// ---------------- GCN ----------------
__global__ __launch_bounds__(256) void k_hh1(const float* __restrict__ bag,
    const float* __restrict__ w1, float* __restrict__ hh1)
{
    int i = blockIdx.x, t = threadIdx.x;
    if (i >= BB) { hh1[(size_t)i * 256 + t] = 0.f; return; }
    float acc = 0.f;
    for (int k2 = 0; k2 < 512; ++k2) acc += bag[i * 512 + k2] * w1[(size_t)k2 * 256 + t];
    hh1[(size_t)i * 256 + t] = acc;
}

__global__ __launch_bounds__(256) void k_g1(const float* __restrict__ hh1,
    const int* __restrict__ idxb, const float* __restrict__ wgt,
    const float* __restrict__ dinvb, const float* __restrict__ b1, float* __restrict__ g)
{
    __shared__ float cf[KNN];
    __shared__ int src[KNN];
    int i = blockIdx.x, t = threadIdx.x;
    if (t < KNN) {
        int s2 = idxb[i * KNN + t];
        src[t] = s2;
        cf[t] = wgt[i * KNN + t] * dinvb[s2] * dinvb[i];
    }
    __syncthreads();
    float di = dinvb[i];
    float val = hh1[(size_t)i * 256 + t] * di * di + b1[t];
    #pragma unroll
    for (int e = 0; e < KNN; ++e) val += cf[e] * hh1[(size_t)src[e] * 256 + t];
    g[(size_t)i * 256 + t] = fmaxf(val, 0.f);
}

__global__ __launch_bounds__(256) void k_hh2(const float* __restrict__ g,
    const float* __restrict__ w2g, float* __restrict__ hh2)
{
    __shared__ float red[256];
    int i = blockIdx.x, t = threadIdx.x;
    float gg = g[(size_t)i * 256 + t];
    float s0 = blockReduceSum(gg * w2g[t * 2 + 0], red);
    float s1 = blockReduceSum(gg * w2g[t * 2 + 1], red);
    if (t == 0) { hh2[i * 2 + 0] = s0; hh2[i * 2 + 1] = s1; }
}

__global__ void k_gout(const float* __restrict__ hh2, const int* __restrict__ idxb,
    const float* __restrict__ wgt, const float* __restrict__ dinvb,
    const float* __restrict__ b2, float* __restrict__ out)
{
    int t = threadIdx.x;
    if (t < 16) {
        int i = t >> 1, c = t & 1;
        float di = dinvb[i];
        float val = hh2[i * 2 + c] * di * di + b2[c];
        for (int e = 0; e < KNN; ++e) {
            int s2 = idxb[i * KNN + e];
            val += wgt[i * KNN + e] * dinvb[s2] * di * hh2[s2 * 2 + c];
        }
        out[16 + i * 2 + c] = val;
    }
}

extern "C" void kernel_launch(void* const* d_in, const int* in_sizes, int n_in,
                              void* d_out, int out_size, void* d_ws, size_t ws_size,
                              hipStream_t stream)
{
    (void)in_sizes; (void)n_in; (void)out_size;
    const float* x     = (const float*)d_in[0];
    const float* fc1_w = (const float*)d_in[1];
    const float* fc1_b = (const float*)d_in[2];
    const float* cls   = (const float*)d_in[3];
    const float* lp[2][7];
    for (int l = 0; l < 2; ++l)
        for (int j = 0; j < 7; ++j)
            lp[l][j] = (const float*)d_in[4 + l * 7 + j];
    const float* w7 = (const float*)d_in[18]; const float* b7 = (const float*)d_in[19];
    const float* w5 = (const float*)d_in[20]; const float* b5 = (const float*)d_in[21];
    const float* w3 = (const float*)d_in[22]; const float* b3 = (const float*)d_in[23];
    const float* lnf_g = (const float*)d_in[24]; const float* lnf_b = (const float*)d_in[25];
    const float* fc2w = (const float*)d_in[26]; const float* fc2b = (const float*)d_in[27];
    const float* gw1 = (const float*)d_in[28]; const float* gb1 = (const float*)d_in[29];
    const float* gw2 = (const float*)d_in[30]; const float* gb2 = (const float*)d_in[31];
    const float* reh = (const float*)d_in[32];
    float* out = (float*)d_out;

    // Workspace budget: 65,418,024 floats = 261,672,096 bytes (ws has 376 MiB).
    const size_t REQUIRED = 65418024ull * 4ull;
    if (ws_size < REQUIRED) {
        k_diag<<<1, 32, 0, stream>>>(out, (float)ws_size);
        return;
    }

    float* Wf = (float*)d_ws;
    size_t off = 0;
    auto alloc = [&](size_t n) { float* p = Wf + off; off += n; return p; };
    float* h      = alloc((size_t)BB * NTOK * 512);   // 24,924,160
    float* lnstat = alloc((size_t)BB * NTOK * 2);     //     97,360
    float* q      = alloc((size_t)CH * NPAD * 512);   // 12,582,912 (chunk-local)
    float* kbv    = alloc((size_t)CH * NPAD * 512);   // 12,582,912 (k; later pinv arena = 6*SLOT)
    float* vb     = alloc((size_t)CH * NPAD * 512);   // 12,582,912
    float* q_l  = alloc((size_t)CH * HEADS * 256 * 64);  // 524,288
    float* k_l  = alloc((size_t)CH * HEADS * 256 * 64);
    float* out3 = alloc((size_t)CH * HEADS * 256 * 64);
    float* w2   = alloc((size_t)CH * HEADS * 256 * 64);
    float* bag  = alloc(8 * 512);
    float* xn   = alloc((size_t)MAXNN * 512);
    float* hh1  = alloc((size_t)MAXNN * 256);
    float* gbuf = alloc((size_t)MAXNN * 256);
    float* hh2  = alloc(MAXNN * 2);
    float* dinv = alloc(MAXNN);
    float* wgt  = alloc(MAXNN * KNN);
    int*   idxb = (int*)alloc(MAXNN * KNN);

    // pinv scratch overlays kbv (k dead after k_attn3v); 6 slots of SLOT floats
    float* attn2 = kbv;
    float* zA = kbv + (size_t)1 * SLOT;
    float* zB = kbv + (size_t)2 * SLOT;
    float* xz = kbv + (size_t)3 * SLOT;
    float* p1 = kbv + (size_t)4 * SLOT;
    float* p2 = kbv + (size_t)5 * SLOT;

    // fc1 + relu -> h rows 1..6000, then wrap rows + cls
    k_gemm<<<dim3(750, 8), 256, 0, stream>>>(x, fc1_w, fc1_b, BB * NINST, 512, 1, 0,
                                             h, nullptr, nullptr, nullptr, nullptr,
                                             nullptr, nullptr, nullptr);
    k_fixup<<<dim3(BB, 85), 256, 0, stream>>>(h, cls);

    for (int l = 0; l < 2; ++l) {
        const float* ln_g  = lp[l][0];
        const float* ln_b  = lp[l][1];
        const float* qkv_w = lp[l][2];
        const float* out_w = lp[l][3];
        const float* out_b = lp[l][4];
        const float* res_w = lp[l][5];
        const float* res_b = lp[l][6];

        k_lnstat<<<BB * NTOK, 256, 0, stream>>>(h, lnstat);
        for (int c = 0; c < NCHUNK; ++c) {
            int b0 = c * CH;
            k_gemm<<<dim3(384, 24), 256, 0, stream>>>(h, qkv_w, nullptr, CH * NPAD, 1536, 2, b0,
                                                      nullptr, q, kbv, vb, nullptr,
                                                      ln_g, ln_b, lnstat);
            k_landmark<<<32 * 256, 64, 0, stream>>>(q, kbv, q_l, k_l);
            k_attn3v<<<32 * 256, 256, 0, stream>>>(q_l, kbv, vb, out3);   // consumes k
            k_attn2<<<32 * 256, 256, 0, stream>>>(q_l, k_l, attn2);       // k dead: arena ok
            k_pinv_init<<<32, 256, 0, stream>>>(attn2, zA);
            float* zc = zA; float* zn = zB;
            for (int it = 0; it < 6; ++it) {
                k_bgemm<<<dim3(32, 4, 4), 256, 0, stream>>>(attn2, zc, xz, 256, 0.f, 1.f);
                k_bgemm<<<dim3(32, 4, 4), 256, 0, stream>>>(xz, xz, p1, 256, 7.f, -1.f);
                k_bgemm<<<dim3(32, 4, 4), 256, 0, stream>>>(xz, p1, p2, 256, 15.f, -1.f);
                k_bgemm<<<dim3(32, 4, 4), 256, 0, stream>>>(zc, p2, zn, 256, 3.25f, -0.25f);
                float* tmp = zc; zc = zn; zn = tmp;
            }
            k_bgemm<<<dim3(32, 4, 1), 256, 0, stream>>>(zc, out3, w2, 64, 0.f, 1.f);
            k_attn1res<<<32 * NPAD, 256, 0, stream>>>(q, k_l, w2, vb, res_w, res_b, q);
            k_gemm<<<dim3(381, 8), 256, 0, stream>>>(nullptr, out_w, out_b, CH * NTOK, 512, 3, b0,
                                                     h, nullptr, nullptr, nullptr, q,
                                                     nullptr, nullptr, nullptr);
        }
        if (l == 0)
            k_ppeg<<<BB * 512, 256, 0, stream>>>(h, w7, b7, w5, b5, w3, b3);
    }

    k_bag<<<BB, 256, 0, stream>>>(h, lnf_g, lnf_b, bag);
    k_mlp<<<1, 64, 0, stream>>>(bag, fc2w, fc2b, out);
    k_xcat<<<MAXNN, 256, 0, stream>>>(bag, reh, xn);
    k_sim_topk<<<MAXNN, 256, 0, stream>>>(xn, idxb, wgt, dinv);
    k_hh1<<<MAXNN, 256, 0, stream>>>(bag, gw1, hh1);
    k_g1<<<MAXNN, 256, 0, stream>>>(hh1, idxb, wgt, dinv, gb1, gbuf);
    k_hh2<<<MAXNN, 256, 0, stream>>>(gbuf, gw2, hh2);
    k_gout<<<1, 64, 0, stream>>>(hh2, idxb, wgt, dinv, gb2, out);
}